// Round 4
// baseline (170.370 us; speedup 1.0000x reference)
//
#include <hip/hip_runtime.h>
#include <cstddef>

// Problem: b=2,h=16,L=4096,d=16,dv=64, chunk=256. Second-order linear attn.
#define BH    32
#define LSEQ  4096
#define D     16
#define DV    64
#define CS    256
#define NC    16
#define NF    160     // padded feature dim (153 real: 1 const + 16 lin + 120 pair + 16 diag)
#define NZ    65      // 64 v cols + z col
#define KSTEPS 5      // NF/32

typedef short short8 __attribute__((ext_vector_type(8)));
typedef float f32x4 __attribute__((ext_vector_type(4)));

// ws layout (bytes): total ~30.4 MiB
#define OFF_KBF 0u                                   // [BH][LSEQ][16] bf16  (4 MiB)
#define OFF_VT  (4u*1024u*1024u)                     // [BH][NZ][LSEQ] bf16  (17.04 MB; row 64 = ones)
#define OFF_ST  (OFF_VT + (unsigned)(BH*NZ*LSEQ*2)) // [BH][NC][NZ][NF] bf16 (10.65 MB)

__device__ __forceinline__ unsigned f2bf(float x) {
  unsigned u = __float_as_uint(x);
  return (u + 0x7FFFu + ((u >> 16) & 1u)) >> 16;   // RNE; inputs always finite
}
__device__ __forceinline__ short8 zero8() {
  short8 z = {0,0,0,0,0,0,0,0};
  return z;
}

// feature table: d | (e<<8) | (psi_half?1<<16:0).  qx/kx rows have [16]=1, [17]=0.
__device__ __forceinline__ unsigned feat_tbl(int f) {
  if (f == 0)  return 16u | (16u << 8);                       // const: 1*1
  if (f <= 16) return (unsigned)(f - 1) | (16u << 8);         // linear: x_d * 1
  if (f < 137) {                                              // pairs d<e
    int p = f - 17, off = 0;
    for (int d = 0; d < 15; ++d) {
      int cnt = 15 - d;
      if (p < off + cnt) return (unsigned)d | ((unsigned)(d + 1 + p - off) << 8);
      off += cnt;
    }
  }
  if (f < 153) {                                              // diag: psi=0.5*q_d^2, chi=k_d^2
    int d = f - 137;
    return (unsigned)d | ((unsigned)d << 8) | (1u << 16);
  }
  return 17u | (17u << 8);                                    // pad: 0*0
}

// ---------------- pass0: k fp32->bf16 rows  +  V^T bf16 [bh][f][j] (+ones row)
// grid 512: blk -> (bh, 256-row slice jb)
__global__ __launch_bounds__(256) void pass0(const float* __restrict__ k,
                                             const float* __restrict__ v,
                                             unsigned* __restrict__ kbf,
                                             unsigned* __restrict__ vt_u32) {
  __shared__ float tile[64][129];
  int blk = blockIdx.x, bh = blk >> 4, jb = (blk & 15) * 256;
  int t = threadIdx.x;

  // --- k conversion: 256 rows x 16 = 2048 u32 pairs
  {
    const float2* ks = (const float2*)(k + ((size_t)bh * LSEQ + jb) * D);
    unsigned* kd = kbf + ((size_t)bh * LSEQ + jb) * D / 2;
    for (int i = t; i < 2048; i += 256) {
      float2 v2 = ks[i];
      kd[i] = f2bf(v2.x) | (f2bf(v2.y) << 16);
    }
  }

  // --- V^T build
  const float* vb = v + ((size_t)bh * LSEQ + jb) * DV;
  for (int half = 0; half < 2; ++half) {
    __syncthreads();
    for (int i = t; i < 128 * 64; i += 256) {       // read rows (coalesced), transpose to LDS
      int j = i >> 6, f = i & 63;
      tile[f][j] = vb[(half * 128 + j) * DV + f];
    }
    __syncthreads();
    for (int o = t; o < 64 * 64; o += 256) {        // write V^T rows (coalesced u32)
      int f = o >> 6, jp = (o & 63) * 2;
      unsigned p = f2bf(tile[f][jp]) | (f2bf(tile[f][jp + 1]) << 16);
      vt_u32[(size_t)(bh * NZ + f) * (LSEQ / 2) + (jb + half * 128 + jp) / 2] = p;
    }
  }
  if (t < 128) {  // ones row (f = 64): bf16(1.0) = 0x3F80
    vt_u32[(size_t)(bh * NZ + 64) * (LSEQ / 2) + jb / 2 + t] = 0x3F803F80u;
  }
}

// ---------------- pass_a: per-chunk state S_c[feat][col] = sum_j chi(k_j) v'_j  (MFMA)
// 512 blocks (one chunk), 320 threads = 5 waves; wave w -> feat M-tiles {2w,2w+1}.
// Epilogue: LDS transpose -> ST bf16 [bh][c][col][feat].
__global__ __launch_bounds__(320) void pass_a(const float* __restrict__ k,
                                              const unsigned short* __restrict__ vt,
                                              unsigned short* __restrict__ st) {
  __shared__ float kx[32][18];
  __shared__ unsigned tbl[NF];
  __shared__ float tile[NF][67];
  int blk = blockIdx.x, bh = blk >> 4, c = blk & 15;
  const float* kc = k + ((size_t)bh * LSEQ + c * CS) * D;
  const unsigned short* vtb = vt + (size_t)bh * NZ * LSEQ + (size_t)c * CS;
  int t = threadIdx.x, w = t >> 6, lane = t & 63, quad = lane >> 4, n16 = lane & 15;
  if (t < NF) tbl[t] = feat_tbl(t);
  f32x4 acc[2][5];
#pragma unroll
  for (int mm = 0; mm < 2; ++mm)
#pragma unroll
    for (int nt = 0; nt < 5; ++nt) acc[mm][nt] = (f32x4){0.f, 0.f, 0.f, 0.f};

  for (int jt = 0; jt < 8; ++jt) {
    __syncthreads();
    for (int i = t; i < 512; i += 320) {
      int j = i >> 4, dd = i & 15;
      kx[j][dd] = kc[(jt * 32 + j) * D + dd];
    }
    if (t < 32) { kx[t][16] = 1.f; kx[t][17] = 0.f; }
    __syncthreads();
    // chi A-fragments: A[m=feat][k=j]
    short8 afr[2];
#pragma unroll
    for (int mm = 0; mm < 2; ++mm) {
      int feat = (w * 2 + mm) * 16 + n16;
      unsigned tv = tbl[feat];
      int d = tv & 255, e = (tv >> 8) & 255;
      short8 a;
#pragma unroll
      for (int i = 0; i < 8; ++i) {
        int jj = quad * 8 + i;
        a[i] = (short)f2bf(kx[jj][d] * kx[jj][e]);   // chi: no 0.5 (psi carries it)
      }
      afr[mm] = a;
    }
    // B-fragments from V^T (bf16, direct 16B loads); MFMA
#pragma unroll
    for (int nt = 0; nt < 5; ++nt) {
      int ncol = nt * 16 + n16;
      short8 b = zero8();
      if (ncol < NZ) b = *(const short8*)(vtb + (size_t)ncol * LSEQ + jt * 32 + quad * 8);
      acc[0][nt] = __builtin_amdgcn_mfma_f32_16x16x32_bf16(afr[0], b, acc[0][nt], 0, 0, 0);
      acc[1][nt] = __builtin_amdgcn_mfma_f32_16x16x32_bf16(afr[1], b, acc[1][nt], 0, 0, 0);
    }
  }
  __syncthreads();
  // C-layout: row(feat-local) = quad*4+reg, col = n16
#pragma unroll
  for (int mm = 0; mm < 2; ++mm)
#pragma unroll
    for (int nt = 0; nt < 5; ++nt) {
      int col = nt * 16 + n16;
      if (col < NZ) {
#pragma unroll
        for (int r = 0; r < 4; ++r)
          tile[(w * 2 + mm) * 16 + quad * 4 + r][col] = acc[mm][nt][r];
      }
    }
  __syncthreads();
  unsigned short* stc = st + (size_t)(bh * NC + c) * NZ * NF;
  for (int i = t; i < NZ * NF; i += 320) {
    int n = i / NF, kk = i - n * NF;
    stc[i] = (unsigned short)f2bf(tile[kk][n]);
  }
}

// ---------------- pass_b: in-place exclusive prefix over chunks (bf16 io, fp32 run)
__global__ __launch_bounds__(256) void pass_b(unsigned short* __restrict__ st) {
  const int PER = NZ * NF;              // 10400
  const int TOT = BH * PER;             // 332800
  int idx = blockIdx.x * 256 + threadIdx.x;
  if (idx >= TOT) return;
  int bh = idx / PER, r = idx - bh * PER;
  unsigned short* p = st + (size_t)bh * NC * PER + r;
  float run = 0.f;
#pragma unroll
  for (int c = 0; c < NC; ++c) {
    unsigned short uv = p[(size_t)c * PER];
    float val = __uint_as_float(((unsigned)uv) << 16);
    p[(size_t)c * PER] = (unsigned short)f2bf(run);
    run += val;
  }
}

// ---------------- pass_c: O = (psi(Q)·S + causal phi(QK^T)·V') / z   (all MFMA)
// 512 blocks, 512 threads = 8 waves.
// BALANCED tiling: wave w owns 16-query M-tiles {w, 15-w}; causal j-tile counts
// (m>>1)+1 sum to exactly 9 units per wave (was 8 units x 2 tiles on wave 7).
__global__ __launch_bounds__(512) void pass_c(const float* __restrict__ q,
                                              const unsigned short* __restrict__ kbf,
                                              const unsigned short* __restrict__ vt,
                                              const unsigned short* __restrict__ st,
                                              float* __restrict__ out) {
  __shared__ float qx[CS][18];
  __shared__ unsigned tbl[NF];
  __shared__ __align__(16) unsigned short ptile[8][32 * 40];
  __shared__ float zline[CS];
  int blk = blockIdx.x, bh = blk >> 4, c = blk & 15;
  const size_t base = (size_t)bh * LSEQ + (size_t)c * CS;
  const float* qc = q + base * D;
  int t = threadIdx.x, w = t >> 6, lane = t & 63, quad = lane >> 4, n16 = lane & 15;
  const int mtile[2] = {w, 15 - w};

  for (int i = t; i < CS * D; i += 512) {
    int row = i >> 4, dd = i & 15;
    qx[row][dd] = qc[i] * 0.25f;              // d^-0.5
  }
  for (int i = t; i < CS; i += 512) { qx[i][16] = 1.f; qx[i][17] = 0.f; }
  if (t < NF) tbl[t] = feat_tbl(t);
  __syncthreads();

  f32x4 acc[2][5];
#pragma unroll
  for (int mm = 0; mm < 2; ++mm)
#pragma unroll
    for (int nt = 0; nt < 5; ++nt) acc[mm][nt] = (f32x4){0.f, 0.f, 0.f, 0.f};

  // ---- inter: acc += psi(Q) · S_prefix   (skip chunk 0: prefix state is zero)
  if (c > 0) {
    const unsigned short* stc = st + (size_t)(bh * NC + c) * NZ * NF;
    for (int ks = 0; ks < KSTEPS; ++ks) {
      short8 afr[2];
#pragma unroll
      for (int mm = 0; mm < 2; ++mm) {
        const float* qrow = qx[mtile[mm] * 16 + n16];
        short8 a;
#pragma unroll
        for (int i = 0; i < 8; ++i) {
          int f = ks * 32 + quad * 8 + i;
          unsigned tv = tbl[f];
          float val = qrow[tv & 255] * qrow[(tv >> 8) & 255];
          if (tv & 0x10000u) val *= 0.5f;
          a[i] = (short)f2bf(val);
        }
        afr[mm] = a;
      }
#pragma unroll
      for (int nt = 0; nt < 5; ++nt) {
        int ncol = nt * 16 + n16;
        short8 b = zero8();
        if (ncol < NZ) b = *(const short8*)(stc + (size_t)ncol * NF + ks * 32 + quad * 8);
        acc[0][nt] = __builtin_amdgcn_mfma_f32_16x16x32_bf16(afr[0], b, acc[0][nt], 0, 0, 0);
        acc[1][nt] = __builtin_amdgcn_mfma_f32_16x16x32_bf16(afr[1], b, acc[1][nt], 0, 0, 0);
      }
    }
  }

  // ---- intra: causal phi attention over j-tiles of 32 keys, per M-tile
  short8 qfr[2];
#pragma unroll
  for (int mm = 0; mm < 2; ++mm) {
    int m = mtile[mm];
    short8 a = zero8();
    if (quad < 2) {
#pragma unroll
      for (int i = 0; i < 8; ++i) a[i] = (short)f2bf(qx[m * 16 + n16][quad * 8 + i]);
    }
    qfr[mm] = a;
  }
  const unsigned short* kbc = kbf + base * D;
  const unsigned short* vtb = vt + (size_t)bh * NZ * LSEQ + (size_t)c * CS;
  short8 ones;
#pragma unroll
  for (int i = 0; i < 8; ++i) ones[i] = (short)0x3F80;

#pragma unroll
  for (int mm = 0; mm < 2; ++mm) {
    int m = mtile[mm];
    int jtmax = m >> 1;                       // inclusive last j-tile
    unsigned short* pwm = &ptile[w][mm * 16 * 40];
    for (int jt = 0; jt <= jtmax; ++jt) {
      // S = Q K^T  (K=16 padded to 32: quads 2,3 zero on both sides)
      short8 kb[2];
#pragma unroll
      for (int ntk = 0; ntk < 2; ++ntk) {
        short8 b = zero8();
        if (quad < 2)
          b = *(const short8*)(kbc + (size_t)(jt * 32 + ntk * 16 + n16) * D + quad * 8);
        kb[ntk] = b;
      }
      f32x4 zf = (f32x4){0.f, 0.f, 0.f, 0.f};
      f32x4 s[2];
#pragma unroll
      for (int ntk = 0; ntk < 2; ++ntk)
        s[ntk] = __builtin_amdgcn_mfma_f32_16x16x32_bf16(qfr[mm], kb[ntk], zf, 0, 0, 0);
      // phi + causal mask -> P tile (per-wave LDS, C-layout -> A-layout)
      bool dtile = (jt == jtmax);
#pragma unroll
      for (int ntk = 0; ntk < 2; ++ntk)
#pragma unroll
        for (int r = 0; r < 4; ++r) {
          float sv = s[ntk][r];
          float phi = fmaf(0.5f * sv, sv, sv) + 1.0f;
          if (dtile) {
            int kcolg = jt * 32 + ntk * 16 + n16;
            int qrowg = m * 16 + quad * 4 + r;
            if (kcolg > qrowg) phi = 0.f;
          }
          pwm[(quad * 4 + r) * 40 + ntk * 16 + n16] = (unsigned short)f2bf(phi);
        }
      // P·V' (z via ones column 64)
      short8 pa = *(const short8*)(pwm + n16 * 40 + quad * 8);
#pragma unroll
      for (int nt = 0; nt < 5; ++nt) {
        int ncol = nt * 16 + n16;
        short8 b;
        if (ncol < 64)       b = *(const short8*)(vtb + (size_t)ncol * LSEQ + jt * 32 + quad * 8);
        else if (ncol == 64) b = ones;
        else                 b = zero8();
        acc[mm][nt] = __builtin_amdgcn_mfma_f32_16x16x32_bf16(pa, b, acc[mm][nt], 0, 0, 0);
      }
    }
  }

  // ---- epilogue: z broadcast via per-wave LDS rows, normalize, store
  if (n16 == 0) {
#pragma unroll
    for (int mm = 0; mm < 2; ++mm)
#pragma unroll
      for (int r = 0; r < 4; ++r)
        zline[mtile[mm] * 16 + quad * 4 + r] = acc[mm][4][r];
  }
  float* oc = out + base * DV;
#pragma unroll
  for (int mm = 0; mm < 2; ++mm)
#pragma unroll
    for (int r = 0; r < 4; ++r) {
      int qrow = mtile[mm] * 16 + quad * 4 + r;
      float inv = 1.0f / (zline[qrow] + 1e-6f);
#pragma unroll
      for (int nt = 0; nt < 4; ++nt)
        oc[(size_t)qrow * DV + nt * 16 + n16] = acc[mm][nt][r] * inv;
    }
}

extern "C" void kernel_launch(void* const* d_in, const int* in_sizes, int n_in,
                              void* d_out, int out_size, void* d_ws, size_t ws_size,
                              hipStream_t stream) {
  (void)in_sizes; (void)n_in; (void)out_size; (void)ws_size;
  const float* q = (const float*)d_in[0];
  const float* k = (const float*)d_in[1];
  const float* v = (const float*)d_in[2];
  char* wsb = (char*)d_ws;
  unsigned*       kbf32 = (unsigned*)(wsb + OFF_KBF);
  unsigned short* kbf   = (unsigned short*)(wsb + OFF_KBF);
  unsigned short* vtp   = (unsigned short*)(wsb + OFF_VT);
  unsigned short* stp   = (unsigned short*)(wsb + OFF_ST);

  pass0<<<512, 256, 0, stream>>>(k, v, kbf32, (unsigned*)vtp);
  pass_a<<<BH * NC, 320, 0, stream>>>(k, vtp, stp);
  pass_b<<<1300, 256, 0, stream>>>(stp);
  pass_c<<<BH * NC, 512, 0, stream>>>(q, kbf, vtp, stp, (float*)d_out);
}

// Round 5
// 134.755 us; speedup vs baseline: 1.2643x; 1.2643x over previous
//
#include <hip/hip_runtime.h>
#include <cstddef>

// Problem: b=2,h=16,L=4096,d=16,dv=64, chunk=256. Second-order linear attn.
#define BH    32
#define LSEQ  4096
#define D     16
#define DV    64
#define CS    256
#define NC    16
#define NF    160     // padded feature dim (153 real: 1 const + 16 lin + 120 pair + 16 diag)
#define NZ    65      // 64 v cols + z col
#define KSTEPS 5      // NF/32

typedef short short8 __attribute__((ext_vector_type(8)));
typedef float f32x4 __attribute__((ext_vector_type(4)));

// ws layout (bytes): total ~30.4 MiB
#define OFF_KBF 0u                                   // [BH][LSEQ][16] bf16  (4 MiB)
#define OFF_VT  (4u*1024u*1024u)                     // [BH][NZ][LSEQ] bf16  (17.04 MB; row 64 = ones)
#define OFF_ST  (OFF_VT + (unsigned)(BH*NZ*LSEQ*2)) // [BH][NC][NZ][NF] bf16 (10.65 MB)

__device__ __forceinline__ unsigned f2bf(float x) {
  unsigned u = __float_as_uint(x);
  return (u + 0x7FFFu + ((u >> 16) & 1u)) >> 16;   // RNE; inputs always finite
}
__device__ __forceinline__ short8 zero8() {
  short8 z = {0,0,0,0,0,0,0,0};
  return z;
}

// feature table: d | (e<<8) | (psi_half?1<<16:0).  qx/kx rows have [16]=1, [17]=0.
__device__ __forceinline__ unsigned feat_tbl(int f) {
  if (f == 0)  return 16u | (16u << 8);                       // const: 1*1
  if (f <= 16) return (unsigned)(f - 1) | (16u << 8);         // linear: x_d * 1
  if (f < 137) {                                              // pairs d<e
    int p = f - 17, off = 0;
    for (int d = 0; d < 15; ++d) {
      int cnt = 15 - d;
      if (p < off + cnt) return (unsigned)d | ((unsigned)(d + 1 + p - off) << 8);
      off += cnt;
    }
  }
  if (f < 153) {                                              // diag: psi=0.5*q_d^2, chi=k_d^2
    int d = f - 137;
    return (unsigned)d | ((unsigned)d << 8) | (1u << 16);
  }
  return 17u | (17u << 8);                                    // pad: 0*0
}

// ---------------- pass_a (fused): per chunk —
//   k fp32 -> bf16 write-through; V^T tile built in LDS + written to global;
//   state S_c = chi(K)^T V' via MFMA with B-frags from LDS;
//   epilogue stores st bf16 [col][feat] directly from C-regs (packed uint2).
// 512 blocks, 320 threads = 5 waves; wave w -> feat M-tiles {2w,2w+1}.
__global__ __launch_bounds__(320) void pass_a(const float* __restrict__ k,
                                              const float* __restrict__ v,
                                              unsigned* __restrict__ kbf_u32,
                                              unsigned* __restrict__ vt_u32,
                                              unsigned short* __restrict__ st) {
  __shared__ float kx[CS][18];                       // 18432 B
  __shared__ __align__(16) unsigned short vt_lds[NZ][264];  // 34320 B (264: 16B-mult stride, 2-way-free banks)
  __shared__ unsigned tbl[NF];
  int blk = blockIdx.x, bh = blk >> 4, c = blk & 15;
  int t = threadIdx.x, w = t >> 6, lane = t & 63, quad = lane >> 4, n16 = lane & 15;

  // --- k chunk: fp32 -> LDS fp32 + global bf16 write-through
  {
    const float2* kc2 = (const float2*)(k + ((size_t)bh * LSEQ + c * CS) * D);
    unsigned* kbd = kbf_u32 + ((size_t)bh * LSEQ + c * CS) * D / 2;
    for (int i = t; i < 2048; i += 320) {
      float2 v2 = kc2[i];
      kbd[i] = f2bf(v2.x) | (f2bf(v2.y) << 16);
      int j = i >> 3, dd = (i & 7) * 2;
      kx[j][dd] = v2.x; kx[j][dd + 1] = v2.y;
    }
    for (int i = t; i < CS; i += 320) { kx[i][16] = 1.f; kx[i][17] = 0.f; }
  }
  // --- v chunk: transpose into vt_lds bf16 + ones row
  {
    const float* vb = v + ((size_t)bh * LSEQ + c * CS) * DV;
    for (int i = t; i < CS * DV; i += 320) {
      int j = i >> 6, f = i & 63;
      vt_lds[f][j] = (unsigned short)f2bf(vb[i]);
    }
    for (int i = t; i < CS; i += 320) vt_lds[64][i] = (unsigned short)0x3F80;
  }
  if (t < NF) tbl[t] = feat_tbl(t);
  __syncthreads();

  // --- write V^T tile to global (coalesced u32)
  {
    unsigned* vtg = vt_u32 + (size_t)bh * NZ * (LSEQ / 2) + c * (CS / 2);
    for (int i = t; i < NZ * (CS / 2); i += 320) {
      int f = i >> 7, jp = (i & 127) * 2;
      vtg[(size_t)f * (LSEQ / 2) + (i & 127)] =
          (unsigned)vt_lds[f][jp] | ((unsigned)vt_lds[f][jp + 1] << 16);
    }
  }

  // --- MFMA: S[feat][col] += chi(k_j)[feat] * v'_j[col]
  f32x4 acc[2][5];
#pragma unroll
  for (int mm = 0; mm < 2; ++mm)
#pragma unroll
    for (int nt = 0; nt < 5; ++nt) acc[mm][nt] = (f32x4){0.f, 0.f, 0.f, 0.f};

  for (int jt = 0; jt < 8; ++jt) {
    short8 afr[2];
#pragma unroll
    for (int mm = 0; mm < 2; ++mm) {
      int feat = (w * 2 + mm) * 16 + n16;
      unsigned tv = tbl[feat];
      int d = tv & 255, e = (tv >> 8) & 255;
      short8 a;
#pragma unroll
      for (int i = 0; i < 8; ++i) {
        int jj = jt * 32 + quad * 8 + i;
        a[i] = (short)f2bf(kx[jj][d] * kx[jj][e]);   // chi: no 0.5 (psi carries it)
      }
      afr[mm] = a;
    }
#pragma unroll
    for (int nt = 0; nt < 5; ++nt) {
      int ncol = nt * 16 + n16;
      short8 b = zero8();
      if (ncol < NZ) b = *(const short8*)(&vt_lds[ncol][jt * 32 + quad * 8]);
      acc[0][nt] = __builtin_amdgcn_mfma_f32_16x16x32_bf16(afr[0], b, acc[0][nt], 0, 0, 0);
      acc[1][nt] = __builtin_amdgcn_mfma_f32_16x16x32_bf16(afr[1], b, acc[1][nt], 0, 0, 0);
    }
  }

  // --- epilogue: pack 4 consecutive feats (quad*4+r) as bf16x4, store [col][feat]
  unsigned short* stc = st + (size_t)(bh * NC + c) * NZ * NF;
#pragma unroll
  for (int mm = 0; mm < 2; ++mm)
#pragma unroll
    for (int nt = 0; nt < 5; ++nt) {
      int col = nt * 16 + n16;
      if (col < NZ) {
        unsigned lo = f2bf(acc[mm][nt][0]) | (f2bf(acc[mm][nt][1]) << 16);
        unsigned hi = f2bf(acc[mm][nt][2]) | (f2bf(acc[mm][nt][3]) << 16);
        int feat0 = (w * 2 + mm) * 16 + quad * 4;
        *(uint2*)(stc + (size_t)col * NF + feat0) = make_uint2(lo, hi);
      }
    }
}

// ---------------- pass_b: in-place exclusive prefix over chunks (bf16 io, fp32 run)
__global__ __launch_bounds__(256) void pass_b(unsigned short* __restrict__ st) {
  const int PER = NZ * NF;              // 10400
  const int TOT = BH * PER;             // 332800
  int idx = blockIdx.x * 256 + threadIdx.x;
  if (idx >= TOT) return;
  int bh = idx / PER, r = idx - bh * PER;
  unsigned short* p = st + (size_t)bh * NC * PER + r;
  float run = 0.f;
#pragma unroll
  for (int c = 0; c < NC; ++c) {
    unsigned short uv = p[(size_t)c * PER];
    float val = __uint_as_float(((unsigned)uv) << 16);
    p[(size_t)c * PER] = (unsigned short)f2bf(run);
    run += val;
  }
}

// ---------------- pass_c: O = (psi(Q)·S + causal phi(QK^T)·V') / z   (all MFMA)
// 512 blocks, 512 threads = 8 waves; wave w -> query M-tiles {2w,2w+1}.
// R3 interleaved structure: both M-tiles advance in one jt loop (2 indep chains).
__global__ __launch_bounds__(512) void pass_c(const float* __restrict__ q,
                                              const unsigned short* __restrict__ kbf,
                                              const unsigned short* __restrict__ vt,
                                              const unsigned short* __restrict__ st,
                                              float* __restrict__ out) {
  __shared__ float qx[CS][18];
  __shared__ unsigned tbl[NF];
  __shared__ __align__(16) unsigned short ptile[8][32 * 40];
  __shared__ float zline[CS];
  int blk = blockIdx.x, bh = blk >> 4, c = blk & 15;
  const size_t base = (size_t)bh * LSEQ + (size_t)c * CS;
  const float* qc = q + base * D;
  int t = threadIdx.x, w = t >> 6, lane = t & 63, quad = lane >> 4, n16 = lane & 15;

  for (int i = t; i < CS * D; i += 512) {
    int row = i >> 4, dd = i & 15;
    qx[row][dd] = qc[i] * 0.25f;              // d^-0.5
  }
  for (int i = t; i < CS; i += 512) { qx[i][16] = 1.f; qx[i][17] = 0.f; }
  if (t < NF) tbl[t] = feat_tbl(t);
  __syncthreads();

  f32x4 acc[2][5];
#pragma unroll
  for (int mm = 0; mm < 2; ++mm)
#pragma unroll
    for (int nt = 0; nt < 5; ++nt) acc[mm][nt] = (f32x4){0.f, 0.f, 0.f, 0.f};

  // ---- inter: acc += psi(Q) · S_prefix  (skip chunk 0: prefix is zero)
  if (c > 0) {
    const unsigned short* stc = st + (size_t)(bh * NC + c) * NZ * NF;
    for (int ks = 0; ks < KSTEPS; ++ks) {
      short8 afr[2];
#pragma unroll
      for (int mm = 0; mm < 2; ++mm) {
        const float* qrow = qx[(w * 2 + mm) * 16 + n16];
        short8 a;
#pragma unroll
        for (int i = 0; i < 8; ++i) {
          int f = ks * 32 + quad * 8 + i;
          unsigned tv = tbl[f];
          float val = qrow[tv & 255] * qrow[(tv >> 8) & 255];
          if (tv & 0x10000u) val *= 0.5f;
          a[i] = (short)f2bf(val);
        }
        afr[mm] = a;
      }
#pragma unroll
      for (int nt = 0; nt < 5; ++nt) {
        int ncol = nt * 16 + n16;
        short8 b = zero8();
        if (ncol < NZ) b = *(const short8*)(stc + (size_t)ncol * NF + ks * 32 + quad * 8);
        acc[0][nt] = __builtin_amdgcn_mfma_f32_16x16x32_bf16(afr[0], b, acc[0][nt], 0, 0, 0);
        acc[1][nt] = __builtin_amdgcn_mfma_f32_16x16x32_bf16(afr[1], b, acc[1][nt], 0, 0, 0);
      }
    }
  }

  // ---- intra: causal phi attention, j-tiles of 32 keys, jt <= w only
  short8 qfr[2];
#pragma unroll
  for (int mm = 0; mm < 2; ++mm) {
    int m = (w * 2 + mm) * 16 + n16;
    short8 a = zero8();
    if (quad < 2) {
#pragma unroll
      for (int i = 0; i < 8; ++i) a[i] = (short)f2bf(qx[m][quad * 8 + i]);
    }
    qfr[mm] = a;
  }
  const unsigned short* kbc = kbf + base * D;
  const unsigned short* vtb = vt + (size_t)bh * NZ * LSEQ + (size_t)c * CS;
  unsigned short* pw = &ptile[w][0];
  short8 ones;
#pragma unroll
  for (int i = 0; i < 8; ++i) ones[i] = (short)0x3F80;

  for (int jt = 0; jt <= w; ++jt) {
    // S = Q K^T  (K=16 padded to 32: quads 2,3 are zero on both sides)
    short8 kb[2];
#pragma unroll
    for (int ntk = 0; ntk < 2; ++ntk) {
      short8 b = zero8();
      if (quad < 2)
        b = *(const short8*)(kbc + (size_t)(jt * 32 + ntk * 16 + n16) * D + quad * 8);
      kb[ntk] = b;
    }
    f32x4 zf = (f32x4){0.f, 0.f, 0.f, 0.f};
    f32x4 s[2][2];
#pragma unroll
    for (int mm = 0; mm < 2; ++mm)
#pragma unroll
      for (int ntk = 0; ntk < 2; ++ntk)
        s[mm][ntk] = __builtin_amdgcn_mfma_f32_16x16x32_bf16(qfr[mm], kb[ntk], zf, 0, 0, 0);
    // phi + causal mask -> P tile (per-wave LDS, C-layout -> A-layout)
    bool diag = (jt == w);
#pragma unroll
    for (int mm = 0; mm < 2; ++mm)
#pragma unroll
      for (int ntk = 0; ntk < 2; ++ntk)
#pragma unroll
        for (int r = 0; r < 4; ++r) {
          float sv = s[mm][ntk][r];
          float phi = fmaf(0.5f * sv, sv, sv) + 1.0f;
          if (diag) {
            int qrow = mm * 16 + quad * 4 + r;
            int kcol = ntk * 16 + n16;
            if (kcol > qrow) phi = 0.f;
          }
          pw[(mm * 16 + quad * 4 + r) * 40 + ntk * 16 + n16] = (unsigned short)f2bf(phi);
        }
    // P·V' (z via ones column 64)
    short8 pa[2];
#pragma unroll
    for (int mm = 0; mm < 2; ++mm)
      pa[mm] = *(const short8*)(pw + (mm * 16 + n16) * 40 + quad * 8);
#pragma unroll
    for (int nt = 0; nt < 5; ++nt) {
      int ncol = nt * 16 + n16;
      short8 b;
      if (ncol < 64)       b = *(const short8*)(vtb + (size_t)ncol * LSEQ + jt * 32 + quad * 8);
      else if (ncol == 64) b = ones;
      else                 b = zero8();
      acc[0][nt] = __builtin_amdgcn_mfma_f32_16x16x32_bf16(pa[0], b, acc[0][nt], 0, 0, 0);
      acc[1][nt] = __builtin_amdgcn_mfma_f32_16x16x32_bf16(pa[1], b, acc[1][nt], 0, 0, 0);
    }
  }

  // ---- epilogue: z broadcast via per-wave LDS rows, normalize, store
  if (n16 == 0) {
#pragma unroll
    for (int mm = 0; mm < 2; ++mm)
#pragma unroll
      for (int r = 0; r < 4; ++r)
        zline[(w * 2 + mm) * 16 + quad * 4 + r] = acc[mm][4][r];
  }
  float* oc = out + base * DV;
#pragma unroll
  for (int mm = 0; mm < 2; ++mm)
#pragma unroll
    for (int r = 0; r < 4; ++r) {
      int qrow = (w * 2 + mm) * 16 + quad * 4 + r;
      float inv = 1.0f / (zline[qrow] + 1e-6f);
#pragma unroll
      for (int nt = 0; nt < 4; ++nt)
        oc[(size_t)qrow * DV + nt * 16 + n16] = acc[mm][nt][r] * inv;
    }
}

extern "C" void kernel_launch(void* const* d_in, const int* in_sizes, int n_in,
                              void* d_out, int out_size, void* d_ws, size_t ws_size,
                              hipStream_t stream) {
  (void)in_sizes; (void)n_in; (void)out_size; (void)ws_size;
  const float* q = (const float*)d_in[0];
  const float* k = (const float*)d_in[1];
  const float* v = (const float*)d_in[2];
  char* wsb = (char*)d_ws;
  unsigned*       kbf32 = (unsigned*)(wsb + OFF_KBF);
  unsigned short* kbf   = (unsigned short*)(wsb + OFF_KBF);
  unsigned short* vtp   = (unsigned short*)(wsb + OFF_VT);
  unsigned short* stp   = (unsigned short*)(wsb + OFF_ST);

  pass_a<<<BH * NC, 320, 0, stream>>>(k, v, kbf32, (unsigned*)vtp, stp);
  pass_b<<<1300, 256, 0, stream>>>(stp);
  pass_c<<<BH * NC, 512, 0, stream>>>(q, kbf, vtp, stp, (float*)d_out);
}

// Round 6
// 134.449 us; speedup vs baseline: 1.2672x; 1.0023x over previous
//
#include <hip/hip_runtime.h>
#include <hip/hip_cooperative_groups.h>
#include <cstddef>

// Problem: b=2,h=16,L=4096,d=16,dv=64, chunk=256. Second-order linear attn.
#define BH    32
#define LSEQ  4096
#define D     16
#define DV    64
#define CS    256
#define NC    16
#define NF    160     // padded feature dim (153 real: 1 const + 16 lin + 120 pair + 16 diag)
#define NZ    65      // 64 v cols + z col
#define KSTEPS 5      // NF/32
#define PER   (NZ * NF)   // 10400 state elems per (bh, chunk)

typedef short short8 __attribute__((ext_vector_type(8)));
typedef float f32x4 __attribute__((ext_vector_type(4)));

// ws layout (bytes): total ~30.4 MiB
#define OFF_KBF 0u                                   // [BH][LSEQ][16] bf16  (4 MiB)
#define OFF_VT  (4u*1024u*1024u)                     // [BH][NZ][LSEQ] bf16  (17.04 MB; row 64 = ones)
#define OFF_ST  (OFF_VT + (unsigned)(BH*NZ*LSEQ*2)) // [BH][NC][NZ][NF] bf16 (10.65 MB)

__device__ __forceinline__ unsigned f2bf(float x) {
  unsigned u = __float_as_uint(x);
  return (u + 0x7FFFu + ((u >> 16) & 1u)) >> 16;   // RNE; inputs always finite
}
__device__ __forceinline__ float bf2f(unsigned short u) {
  return __uint_as_float(((unsigned)u) << 16);
}
__device__ __forceinline__ short8 zero8() {
  short8 z = {0,0,0,0,0,0,0,0};
  return z;
}

// feature table: d | (e<<8) | (psi_half?1<<16:0).  qx/kx rows have [16]=1, [17]=0.
__device__ __forceinline__ unsigned feat_tbl(int f) {
  if (f == 0)  return 16u | (16u << 8);                       // const: 1*1
  if (f <= 16) return (unsigned)(f - 1) | (16u << 8);         // linear: x_d * 1
  if (f < 137) {                                              // pairs d<e
    int p = f - 17, off = 0;
    for (int d = 0; d < 15; ++d) {
      int cnt = 15 - d;
      if (p < off + cnt) return (unsigned)d | ((unsigned)(d + 1 + p - off) << 8);
      off += cnt;
    }
  }
  if (f < 153) {                                              // diag: psi=0.5*q_d^2, chi=k_d^2
    int d = f - 137;
    return (unsigned)d | ((unsigned)d << 8) | (1u << 16);
  }
  return 17u | (17u << 8);                                    // pad: 0*0
}

// =================== UNIFIED cooperative kernel ===================
// 512 blocks x 512 threads, 2 blocks/CU. Phase A (state build) -> grid.sync()
// -> per-block prefix sum into LDS -> Phase C (inter + intra + normalize).
struct SmemA {
  float kx[CS][18];                                    // 18432 B
  __align__(16) unsigned short vt[NZ][264];            // 34320 B
};
struct SmemC {
  float qx[CS][18];                                    // 18432 B
  __align__(16) unsigned short st[NZ][168];            // 21840 B
  __align__(16) unsigned short ptile[8][1280];         // 20480 B
  float zline[CS];                                     // 1024 B
};
union SmemU { SmemA a; SmemC c; };                     // 61776 B

__global__ __launch_bounds__(512, 4) void unified(const float* __restrict__ q,
                                                  const float* __restrict__ k,
                                                  const float* __restrict__ v,
                                                  unsigned* __restrict__ kbf_u32,
                                                  unsigned* __restrict__ vt_u32,
                                                  unsigned short* __restrict__ st,
                                                  float* __restrict__ out) {
  __shared__ SmemU sm;
  __shared__ unsigned tbl[NF];
  int blk = blockIdx.x, bh = blk >> 4, c = blk & 15;
  int t = threadIdx.x, w = t >> 6, lane = t & 63, quad = lane >> 4, n16 = lane & 15;
  const size_t base = (size_t)bh * LSEQ + (size_t)c * CS;

  // ---------------- Phase A ----------------
  {
    const float2* kc2 = (const float2*)(k + base * D);
    unsigned* kbd = kbf_u32 + base * D / 2;
    for (int i = t; i < 2048; i += 512) {
      float2 v2 = kc2[i];
      kbd[i] = f2bf(v2.x) | (f2bf(v2.y) << 16);
      int j = i >> 3, dd = (i & 7) * 2;
      sm.a.kx[j][dd] = v2.x; sm.a.kx[j][dd + 1] = v2.y;
    }
    for (int i = t; i < CS; i += 512) { sm.a.kx[i][16] = 1.f; sm.a.kx[i][17] = 0.f; }
    const float* vb = v + base * DV;
    for (int i = t; i < CS * DV; i += 512) {
      int j = i >> 6, f = i & 63;
      sm.a.vt[f][j] = (unsigned short)f2bf(vb[i]);
    }
    for (int i = t; i < CS; i += 512) sm.a.vt[64][i] = (unsigned short)0x3F80;
    if (t < NF) tbl[t] = feat_tbl(t);
  }
  __syncthreads();
  {
    unsigned* vtg = vt_u32 + (size_t)bh * NZ * (LSEQ / 2) + c * (CS / 2);
    for (int i = t; i < NZ * (CS / 2); i += 512) {
      int f = i >> 7, jp = (i & 127) * 2;
      vtg[(size_t)f * (LSEQ / 2) + (i & 127)] =
          (unsigned)sm.a.vt[f][jp] | ((unsigned)sm.a.vt[f][jp + 1] << 16);
    }
  }
  if (w < 5) {   // waves 0..4: feat M-tiles {2w, 2w+1}
    f32x4 acc[2][5];
#pragma unroll
    for (int mm = 0; mm < 2; ++mm)
#pragma unroll
      for (int nt = 0; nt < 5; ++nt) acc[mm][nt] = (f32x4){0.f, 0.f, 0.f, 0.f};
    for (int jt = 0; jt < 8; ++jt) {
      short8 afr[2];
#pragma unroll
      for (int mm = 0; mm < 2; ++mm) {
        int feat = (w * 2 + mm) * 16 + n16;
        unsigned tv = tbl[feat];
        int d = tv & 255, e = (tv >> 8) & 255;
        short8 a;
#pragma unroll
        for (int i = 0; i < 8; ++i) {
          int jj = jt * 32 + quad * 8 + i;
          a[i] = (short)f2bf(sm.a.kx[jj][d] * sm.a.kx[jj][e]);  // chi (psi carries the 0.5)
        }
        afr[mm] = a;
      }
#pragma unroll
      for (int nt = 0; nt < 5; ++nt) {
        int ncol = nt * 16 + n16;
        short8 b = zero8();
        if (ncol < NZ) b = *(const short8*)(&sm.a.vt[ncol][jt * 32 + quad * 8]);
        acc[0][nt] = __builtin_amdgcn_mfma_f32_16x16x32_bf16(afr[0], b, acc[0][nt], 0, 0, 0);
        acc[1][nt] = __builtin_amdgcn_mfma_f32_16x16x32_bf16(afr[1], b, acc[1][nt], 0, 0, 0);
      }
    }
    unsigned short* stc = st + (size_t)(bh * NC + c) * PER;
#pragma unroll
    for (int mm = 0; mm < 2; ++mm)
#pragma unroll
      for (int nt = 0; nt < 5; ++nt) {
        int col = nt * 16 + n16;
        if (col < NZ) {
          unsigned lo = f2bf(acc[mm][nt][0]) | (f2bf(acc[mm][nt][1]) << 16);
          unsigned hi = f2bf(acc[mm][nt][2]) | (f2bf(acc[mm][nt][3]) << 16);
          int feat0 = (w * 2 + mm) * 16 + quad * 4;
          *(uint2*)(stc + (size_t)col * NF + feat0) = make_uint2(lo, hi);
        }
      }
  }

  // ---------------- grid-wide barrier ----------------
  cooperative_groups::this_grid().sync();

  // ---------------- Phase B: prefix sum of chunks 0..c-1 into LDS ----------------
  {
    const float* qc = q + base * D;
    for (int i = t; i < CS * D; i += 512) {
      int row = i >> 4, dd = i & 15;
      sm.c.qx[row][dd] = qc[i] * 0.25f;          // d^-0.5
    }
    for (int i = t; i < CS; i += 512) { sm.c.qx[i][16] = 1.f; sm.c.qx[i][17] = 0.f; }
    if (c > 0) {
      const unsigned short* stg = st + (size_t)bh * NC * PER;
      for (int i = t; i < PER; i += 512) {
        float s = 0.f;
        for (int cc = 0; cc < c; ++cc) s += bf2f(stg[(size_t)cc * PER + i]);
        int col = i / NF, ft = i - col * NF;
        sm.c.st[col][ft] = (unsigned short)f2bf(s);
      }
    }
  }
  __syncthreads();

  // ---------------- Phase C ----------------
  f32x4 acc[2][5];
#pragma unroll
  for (int mm = 0; mm < 2; ++mm)
#pragma unroll
    for (int nt = 0; nt < 5; ++nt) acc[mm][nt] = (f32x4){0.f, 0.f, 0.f, 0.f};

  // inter: acc += psi(Q) · S_prefix   (skip chunk 0)
  if (c > 0) {
    for (int ks = 0; ks < KSTEPS; ++ks) {
      short8 afr[2];
#pragma unroll
      for (int mm = 0; mm < 2; ++mm) {
        const float* qrow = sm.c.qx[(w * 2 + mm) * 16 + n16];
        short8 a;
#pragma unroll
        for (int i = 0; i < 8; ++i) {
          int f = ks * 32 + quad * 8 + i;
          unsigned tv = tbl[f];
          float val = qrow[tv & 255] * qrow[(tv >> 8) & 255];
          if (tv & 0x10000u) val *= 0.5f;
          a[i] = (short)f2bf(val);
        }
        afr[mm] = a;
      }
#pragma unroll
      for (int nt = 0; nt < 5; ++nt) {
        int ncol = nt * 16 + n16;
        short8 b = zero8();
        if (ncol < NZ) b = *(const short8*)(&sm.c.st[ncol][ks * 32 + quad * 8]);
        acc[0][nt] = __builtin_amdgcn_mfma_f32_16x16x32_bf16(afr[0], b, acc[0][nt], 0, 0, 0);
        acc[1][nt] = __builtin_amdgcn_mfma_f32_16x16x32_bf16(afr[1], b, acc[1][nt], 0, 0, 0);
      }
    }
  }

  // intra: causal phi attention, j-tiles of 32 keys, jt <= w
  short8 qfr[2];
#pragma unroll
  for (int mm = 0; mm < 2; ++mm) {
    int m = (w * 2 + mm) * 16 + n16;
    short8 a = zero8();
    if (quad < 2) {
#pragma unroll
      for (int i = 0; i < 8; ++i) a[i] = (short)f2bf(sm.c.qx[m][quad * 8 + i]);
    }
    qfr[mm] = a;
  }
  const unsigned short* kbc = (const unsigned short*)kbf_u32 + base * D;
  const unsigned short* vtb = (const unsigned short*)vt_u32 + (size_t)bh * NZ * LSEQ + (size_t)c * CS;
  unsigned short* pw = &sm.c.ptile[w][0];
  short8 ones;
#pragma unroll
  for (int i = 0; i < 8; ++i) ones[i] = (short)0x3F80;

  for (int jt = 0; jt <= w; ++jt) {
    short8 kb[2];
#pragma unroll
    for (int ntk = 0; ntk < 2; ++ntk) {
      short8 b = zero8();
      if (quad < 2)
        b = *(const short8*)(kbc + (size_t)(jt * 32 + ntk * 16 + n16) * D + quad * 8);
      kb[ntk] = b;
    }
    f32x4 zf = (f32x4){0.f, 0.f, 0.f, 0.f};
    f32x4 s[2][2];
#pragma unroll
    for (int mm = 0; mm < 2; ++mm)
#pragma unroll
      for (int ntk = 0; ntk < 2; ++ntk)
        s[mm][ntk] = __builtin_amdgcn_mfma_f32_16x16x32_bf16(qfr[mm], kb[ntk], zf, 0, 0, 0);
    bool diag = (jt == w);
#pragma unroll
    for (int mm = 0; mm < 2; ++mm)
#pragma unroll
      for (int ntk = 0; ntk < 2; ++ntk)
#pragma unroll
        for (int r = 0; r < 4; ++r) {
          float sv = s[mm][ntk][r];
          float phi = fmaf(0.5f * sv, sv, sv) + 1.0f;
          if (diag) {
            int qrow = mm * 16 + quad * 4 + r;
            int kcol = ntk * 16 + n16;
            if (kcol > qrow) phi = 0.f;
          }
          pw[(mm * 16 + quad * 4 + r) * 40 + ntk * 16 + n16] = (unsigned short)f2bf(phi);
        }
    short8 pa[2];
#pragma unroll
    for (int mm = 0; mm < 2; ++mm)
      pa[mm] = *(const short8*)(pw + (mm * 16 + n16) * 40 + quad * 8);
#pragma unroll
    for (int nt = 0; nt < 5; ++nt) {
      int ncol = nt * 16 + n16;
      short8 b;
      if (ncol < 64)       b = *(const short8*)(vtb + (size_t)ncol * LSEQ + jt * 32 + quad * 8);
      else if (ncol == 64) b = ones;
      else                 b = zero8();
      acc[0][nt] = __builtin_amdgcn_mfma_f32_16x16x32_bf16(pa[0], b, acc[0][nt], 0, 0, 0);
      acc[1][nt] = __builtin_amdgcn_mfma_f32_16x16x32_bf16(pa[1], b, acc[1][nt], 0, 0, 0);
    }
  }

  // epilogue
  if (n16 == 0) {
#pragma unroll
    for (int mm = 0; mm < 2; ++mm)
#pragma unroll
      for (int r = 0; r < 4; ++r)
        sm.c.zline[(w * 2 + mm) * 16 + quad * 4 + r] = acc[mm][4][r];
  }
  float* oc = out + base * DV;
#pragma unroll
  for (int mm = 0; mm < 2; ++mm)
#pragma unroll
    for (int r = 0; r < 4; ++r) {
      int qrow = (w * 2 + mm) * 16 + quad * 4 + r;
      float inv = 1.0f / (sm.c.zline[qrow] + 1e-6f);
#pragma unroll
      for (int nt = 0; nt < 4; ++nt)
        oc[(size_t)qrow * DV + nt * 16 + n16] = acc[mm][nt][r] * inv;
    }
}

// =================== FALLBACK: proven R5 3-kernel path ===================
__global__ __launch_bounds__(320) void pass_a(const float* __restrict__ k,
                                              const float* __restrict__ v,
                                              unsigned* __restrict__ kbf_u32,
                                              unsigned* __restrict__ vt_u32,
                                              unsigned short* __restrict__ st) {
  __shared__ float kx[CS][18];
  __shared__ __align__(16) unsigned short vt_lds[NZ][264];
  __shared__ unsigned tbl[NF];
  int blk = blockIdx.x, bh = blk >> 4, c = blk & 15;
  int t = threadIdx.x, w = t >> 6, lane = t & 63, quad = lane >> 4, n16 = lane & 15;
  {
    const float2* kc2 = (const float2*)(k + ((size_t)bh * LSEQ + c * CS) * D);
    unsigned* kbd = kbf_u32 + ((size_t)bh * LSEQ + c * CS) * D / 2;
    for (int i = t; i < 2048; i += 320) {
      float2 v2 = kc2[i];
      kbd[i] = f2bf(v2.x) | (f2bf(v2.y) << 16);
      int j = i >> 3, dd = (i & 7) * 2;
      kx[j][dd] = v2.x; kx[j][dd + 1] = v2.y;
    }
    for (int i = t; i < CS; i += 320) { kx[i][16] = 1.f; kx[i][17] = 0.f; }
  }
  {
    const float* vb = v + ((size_t)bh * LSEQ + c * CS) * DV;
    for (int i = t; i < CS * DV; i += 320) {
      int j = i >> 6, f = i & 63;
      vt_lds[f][j] = (unsigned short)f2bf(vb[i]);
    }
    for (int i = t; i < CS; i += 320) vt_lds[64][i] = (unsigned short)0x3F80;
  }
  if (t < NF) tbl[t] = feat_tbl(t);
  __syncthreads();
  {
    unsigned* vtg = vt_u32 + (size_t)bh * NZ * (LSEQ / 2) + c * (CS / 2);
    for (int i = t; i < NZ * (CS / 2); i += 320) {
      int f = i >> 7, jp = (i & 127) * 2;
      vtg[(size_t)f * (LSEQ / 2) + (i & 127)] =
          (unsigned)vt_lds[f][jp] | ((unsigned)vt_lds[f][jp + 1] << 16);
    }
  }
  f32x4 acc[2][5];
#pragma unroll
  for (int mm = 0; mm < 2; ++mm)
#pragma unroll
    for (int nt = 0; nt < 5; ++nt) acc[mm][nt] = (f32x4){0.f, 0.f, 0.f, 0.f};
  for (int jt = 0; jt < 8; ++jt) {
    short8 afr[2];
#pragma unroll
    for (int mm = 0; mm < 2; ++mm) {
      int feat = (w * 2 + mm) * 16 + n16;
      unsigned tv = tbl[feat];
      int d = tv & 255, e = (tv >> 8) & 255;
      short8 a;
#pragma unroll
      for (int i = 0; i < 8; ++i) {
        int jj = jt * 32 + quad * 8 + i;
        a[i] = (short)f2bf(kx[jj][d] * kx[jj][e]);
      }
      afr[mm] = a;
    }
#pragma unroll
    for (int nt = 0; nt < 5; ++nt) {
      int ncol = nt * 16 + n16;
      short8 b = zero8();
      if (ncol < NZ) b = *(const short8*)(&vt_lds[ncol][jt * 32 + quad * 8]);
      acc[0][nt] = __builtin_amdgcn_mfma_f32_16x16x32_bf16(afr[0], b, acc[0][nt], 0, 0, 0);
      acc[1][nt] = __builtin_amdgcn_mfma_f32_16x16x32_bf16(afr[1], b, acc[1][nt], 0, 0, 0);
    }
  }
  unsigned short* stc = st + (size_t)(bh * NC + c) * PER;
#pragma unroll
  for (int mm = 0; mm < 2; ++mm)
#pragma unroll
    for (int nt = 0; nt < 5; ++nt) {
      int col = nt * 16 + n16;
      if (col < NZ) {
        unsigned lo = f2bf(acc[mm][nt][0]) | (f2bf(acc[mm][nt][1]) << 16);
        unsigned hi = f2bf(acc[mm][nt][2]) | (f2bf(acc[mm][nt][3]) << 16);
        int feat0 = (w * 2 + mm) * 16 + quad * 4;
        *(uint2*)(stc + (size_t)col * NF + feat0) = make_uint2(lo, hi);
      }
    }
}

__global__ __launch_bounds__(256) void pass_b(unsigned short* __restrict__ st) {
  const int TOT = BH * PER;
  int idx = blockIdx.x * 256 + threadIdx.x;
  if (idx >= TOT) return;
  int bh = idx / PER, r = idx - bh * PER;
  unsigned short* p = st + (size_t)bh * NC * PER + r;
  float run = 0.f;
#pragma unroll
  for (int c = 0; c < NC; ++c) {
    unsigned short uv = p[(size_t)c * PER];
    float val = bf2f(uv);
    p[(size_t)c * PER] = (unsigned short)f2bf(run);
    run += val;
  }
}

__global__ __launch_bounds__(512) void pass_c(const float* __restrict__ q,
                                              const unsigned short* __restrict__ kbf,
                                              const unsigned short* __restrict__ vt,
                                              const unsigned short* __restrict__ st,
                                              float* __restrict__ out) {
  __shared__ float qx[CS][18];
  __shared__ unsigned tbl[NF];
  __shared__ __align__(16) unsigned short ptile[8][32 * 40];
  __shared__ float zline[CS];
  int blk = blockIdx.x, bh = blk >> 4, c = blk & 15;
  const size_t base = (size_t)bh * LSEQ + (size_t)c * CS;
  const float* qc = q + base * D;
  int t = threadIdx.x, w = t >> 6, lane = t & 63, quad = lane >> 4, n16 = lane & 15;
  for (int i = t; i < CS * D; i += 512) {
    int row = i >> 4, dd = i & 15;
    qx[row][dd] = qc[i] * 0.25f;
  }
  for (int i = t; i < CS; i += 512) { qx[i][16] = 1.f; qx[i][17] = 0.f; }
  if (t < NF) tbl[t] = feat_tbl(t);
  __syncthreads();
  f32x4 acc[2][5];
#pragma unroll
  for (int mm = 0; mm < 2; ++mm)
#pragma unroll
    for (int nt = 0; nt < 5; ++nt) acc[mm][nt] = (f32x4){0.f, 0.f, 0.f, 0.f};
  if (c > 0) {
    const unsigned short* stc = st + (size_t)(bh * NC + c) * PER;
    for (int ks = 0; ks < KSTEPS; ++ks) {
      short8 afr[2];
#pragma unroll
      for (int mm = 0; mm < 2; ++mm) {
        const float* qrow = qx[(w * 2 + mm) * 16 + n16];
        short8 a;
#pragma unroll
        for (int i = 0; i < 8; ++i) {
          int f = ks * 32 + quad * 8 + i;
          unsigned tv = tbl[f];
          float val = qrow[tv & 255] * qrow[(tv >> 8) & 255];
          if (tv & 0x10000u) val *= 0.5f;
          a[i] = (short)f2bf(val);
        }
        afr[mm] = a;
      }
#pragma unroll
      for (int nt = 0; nt < 5; ++nt) {
        int ncol = nt * 16 + n16;
        short8 b = zero8();
        if (ncol < NZ) b = *(const short8*)(stc + (size_t)ncol * NF + ks * 32 + quad * 8);
        acc[0][nt] = __builtin_amdgcn_mfma_f32_16x16x32_bf16(afr[0], b, acc[0][nt], 0, 0, 0);
        acc[1][nt] = __builtin_amdgcn_mfma_f32_16x16x32_bf16(afr[1], b, acc[1][nt], 0, 0, 0);
      }
    }
  }
  short8 qfr[2];
#pragma unroll
  for (int mm = 0; mm < 2; ++mm) {
    int m = (w * 2 + mm) * 16 + n16;
    short8 a = zero8();
    if (quad < 2) {
#pragma unroll
      for (int i = 0; i < 8; ++i) a[i] = (short)f2bf(qx[m][quad * 8 + i]);
    }
    qfr[mm] = a;
  }
  const unsigned short* kbc = kbf + base * D;
  const unsigned short* vtb = vt + (size_t)bh * NZ * LSEQ + (size_t)c * CS;
  unsigned short* pw = &ptile[w][0];
  short8 ones;
#pragma unroll
  for (int i = 0; i < 8; ++i) ones[i] = (short)0x3F80;
  for (int jt = 0; jt <= w; ++jt) {
    short8 kb[2];
#pragma unroll
    for (int ntk = 0; ntk < 2; ++ntk) {
      short8 b = zero8();
      if (quad < 2)
        b = *(const short8*)(kbc + (size_t)(jt * 32 + ntk * 16 + n16) * D + quad * 8);
      kb[ntk] = b;
    }
    f32x4 zf = (f32x4){0.f, 0.f, 0.f, 0.f};
    f32x4 s[2][2];
#pragma unroll
    for (int mm = 0; mm < 2; ++mm)
#pragma unroll
      for (int ntk = 0; ntk < 2; ++ntk)
        s[mm][ntk] = __builtin_amdgcn_mfma_f32_16x16x32_bf16(qfr[mm], kb[ntk], zf, 0, 0, 0);
    bool diag = (jt == w);
#pragma unroll
    for (int mm = 0; mm < 2; ++mm)
#pragma unroll
      for (int ntk = 0; ntk < 2; ++ntk)
#pragma unroll
        for (int r = 0; r < 4; ++r) {
          float sv = s[mm][ntk][r];
          float phi = fmaf(0.5f * sv, sv, sv) + 1.0f;
          if (diag) {
            int qrow = mm * 16 + quad * 4 + r;
            int kcol = ntk * 16 + n16;
            if (kcol > qrow) phi = 0.f;
          }
          pw[(mm * 16 + quad * 4 + r) * 40 + ntk * 16 + n16] = (unsigned short)f2bf(phi);
        }
    short8 pa[2];
#pragma unroll
    for (int mm = 0; mm < 2; ++mm)
      pa[mm] = *(const short8*)(pw + (mm * 16 + n16) * 40 + quad * 8);
#pragma unroll
    for (int nt = 0; nt < 5; ++nt) {
      int ncol = nt * 16 + n16;
      short8 b;
      if (ncol < 64)       b = *(const short8*)(vtb + (size_t)ncol * LSEQ + jt * 32 + quad * 8);
      else if (ncol == 64) b = ones;
      else                 b = zero8();
      acc[0][nt] = __builtin_amdgcn_mfma_f32_16x16x32_bf16(pa[0], b, acc[0][nt], 0, 0, 0);
      acc[1][nt] = __builtin_amdgcn_mfma_f32_16x16x32_bf16(pa[1], b, acc[1][nt], 0, 0, 0);
    }
  }
  if (n16 == 0) {
#pragma unroll
    for (int mm = 0; mm < 2; ++mm)
#pragma unroll
      for (int r = 0; r < 4; ++r)
        zline[(w * 2 + mm) * 16 + quad * 4 + r] = acc[mm][4][r];
  }
  float* oc = out + base * DV;
#pragma unroll
  for (int mm = 0; mm < 2; ++mm)
#pragma unroll
    for (int r = 0; r < 4; ++r) {
      int qrow = (w * 2 + mm) * 16 + quad * 4 + r;
      float inv = 1.0f / (zline[qrow] + 1e-6f);
#pragma unroll
      for (int nt = 0; nt < 4; ++nt)
        oc[(size_t)qrow * DV + nt * 16 + n16] = acc[mm][nt][r] * inv;
    }
}

extern "C" void kernel_launch(void* const* d_in, const int* in_sizes, int n_in,
                              void* d_out, int out_size, void* d_ws, size_t ws_size,
                              hipStream_t stream) {
  (void)in_sizes; (void)n_in; (void)out_size; (void)ws_size;
  const float* q = (const float*)d_in[0];
  const float* k = (const float*)d_in[1];
  const float* v = (const float*)d_in[2];
  float* out = (float*)d_out;
  char* wsb = (char*)d_ws;
  unsigned*       kbf32 = (unsigned*)(wsb + OFF_KBF);
  unsigned short* kbf   = (unsigned short*)(wsb + OFF_KBF);
  unsigned*       vt32  = (unsigned*)(wsb + OFF_VT);
  unsigned short* vtp   = (unsigned short*)(wsb + OFF_VT);
  unsigned short* stp   = (unsigned short*)(wsb + OFF_ST);

  // deterministic per-call path choice (same result every call -> capture-safe)
  int nb = 0;
  hipError_t oe = hipOccupancyMaxActiveBlocksPerMultiprocessor(
      &nb, reinterpret_cast<const void*>(unified), 512, 0);
  if (oe == hipSuccess && nb >= 2) {
    void* args[] = {(void*)&q, (void*)&k, (void*)&v,
                    (void*)&kbf32, (void*)&vt32, (void*)&stp, (void*)&out};
    hipLaunchCooperativeKernel(reinterpret_cast<const void*>(unified),
                               dim3(BH * NC), dim3(512), args, 0, stream);
  } else {
    pass_a<<<BH * NC, 320, 0, stream>>>(k, v, kbf32, vt32, stp);
    pass_b<<<1300, 256, 0, stream>>>(stp);
    pass_c<<<BH * NC, 512, 0, stream>>>(q, kbf, vtp, stp, out);
  }
}

// Round 7
// 130.053 us; speedup vs baseline: 1.3100x; 1.0338x over previous
//
#include <hip/hip_runtime.h>
#include <hip/hip_cooperative_groups.h>
#include <cstddef>

// Problem: b=2,h=16,L=4096,d=16,dv=64, chunk=256. Second-order linear attn.
#define BH    32
#define LSEQ  4096
#define D     16
#define DV    64
#define CS    256
#define NC    16
#define NF    160     // padded feature dim (153 real)
#define NZ    65      // 64 v cols + z col
#define KSTEPS 5      // NF/32
#define PER   (NZ * NF)   // 10400 state elems per (bh, chunk)

typedef short short8 __attribute__((ext_vector_type(8)));
typedef float f32x4 __attribute__((ext_vector_type(4)));

// ws layout (bytes)
#define OFF_KBF 0u                                   // [BH][LSEQ][16] bf16  (4 MiB)
#define OFF_VT  (4u*1024u*1024u)                     // [BH][NZ][LSEQ] bf16 (fallback path only)
#define OFF_ST  (OFF_VT + (unsigned)(BH*NZ*LSEQ*2)) // [BH][NC][NZ][NF] bf16 (10.65 MB)

__device__ __forceinline__ unsigned f2bf(float x) {
  unsigned u = __float_as_uint(x);
  return (u + 0x7FFFu + ((u >> 16) & 1u)) >> 16;   // RNE; inputs always finite
}
__device__ __forceinline__ float bf2f(unsigned short u) {
  return __uint_as_float(((unsigned)u) << 16);
}
__device__ __forceinline__ short8 zero8() {
  short8 z = {0,0,0,0,0,0,0,0};
  return z;
}

// feature table: d | (e<<8) | (psi_half?1<<16:0).  qx/kx rows have [16]=1, [17]=0.
__device__ __forceinline__ unsigned feat_tbl(int f) {
  if (f == 0)  return 16u | (16u << 8);                       // const: 1*1
  if (f <= 16) return (unsigned)(f - 1) | (16u << 8);         // linear: x_d * 1
  if (f < 137) {                                              // pairs d<e
    int p = f - 17, off = 0;
    for (int d = 0; d < 15; ++d) {
      int cnt = 15 - d;
      if (p < off + cnt) return (unsigned)d | ((unsigned)(d + 1 + p - off) << 8);
      off += cnt;
    }
  }
  if (f < 153) {                                              // diag: psi=0.5*q_d^2, chi=k_d^2
    int d = f - 137;
    return (unsigned)d | ((unsigned)d << 8) | (1u << 16);
  }
  return 17u | (17u << 8);                                    // pad: 0*0
}

// =================== UNIFIED cooperative kernel ===================
// 512 blocks x 512 threads, 2 blocks/CU (150.5 KB LDS / CU).
// vt stays in LDS for the whole block lifetime (never round-trips HBM).
struct Smem {
  float kxqx[CS][18];                                   // 18432 B (kx in A, qx in C)
  __align__(16) unsigned short vt[NZ][264];             // 34320 B (persists A -> C)
  union {
    __align__(16) unsigned short stt[NZ][168];          // 21840 B (phase B / inter)
    struct {
      __align__(16) unsigned short ptile[8][1280];      // 20480 B (intra)
      float zline[CS];                                  // 1024 B
    } u;
  } b;
  unsigned tbl[NF];                                     // 640 B
};                                                      // total 75232 B

__global__ __launch_bounds__(512, 4) void unified(const float* __restrict__ q,
                                                  const float* __restrict__ k,
                                                  const float* __restrict__ v,
                                                  unsigned* __restrict__ kbf_u32,
                                                  unsigned short* __restrict__ st,
                                                  float* __restrict__ out) {
  __shared__ Smem sm;
  int blk = blockIdx.x, bh = blk >> 4, c = blk & 15;
  int t = threadIdx.x, w = t >> 6, lane = t & 63, quad = lane >> 4, n16 = lane & 15;
  const size_t base = (size_t)bh * LSEQ + (size_t)c * CS;

  // ---------------- Phase A: load k (fp32 LDS + bf16 global), v^T (bf16 LDS) ----
  {
    const float2* kc2 = (const float2*)(k + base * D);
    unsigned* kbd = kbf_u32 + base * D / 2;
    for (int i = t; i < 2048; i += 512) {
      float2 v2 = kc2[i];
      kbd[i] = f2bf(v2.x) | (f2bf(v2.y) << 16);
      int j = i >> 3, dd = (i & 7) * 2;
      sm.kxqx[j][dd] = v2.x; sm.kxqx[j][dd + 1] = v2.y;
    }
    for (int i = t; i < CS; i += 512) { sm.kxqx[i][16] = 1.f; sm.kxqx[i][17] = 0.f; }
    const float* vb = v + base * DV;
    for (int i = t; i < CS * DV; i += 512) {
      int j = i >> 6, f = i & 63;
      sm.vt[f][j] = (unsigned short)f2bf(vb[i]);
    }
    for (int i = t; i < CS; i += 512) sm.vt[64][i] = (unsigned short)0x3F80;
    if (t < NF) sm.tbl[t] = feat_tbl(t);
  }
  __syncthreads();

  // state MFMA + store (skip c==15: its state is never consumed)
  if (c < 15 && w < 5) {
    f32x4 acc[2][5];
#pragma unroll
    for (int mm = 0; mm < 2; ++mm)
#pragma unroll
      for (int nt = 0; nt < 5; ++nt) acc[mm][nt] = (f32x4){0.f, 0.f, 0.f, 0.f};
    for (int jt = 0; jt < 8; ++jt) {
      short8 afr[2];
#pragma unroll
      for (int mm = 0; mm < 2; ++mm) {
        int feat = (w * 2 + mm) * 16 + n16;
        unsigned tv = sm.tbl[feat];
        int d = tv & 255, e = (tv >> 8) & 255;
        short8 a;
#pragma unroll
        for (int i = 0; i < 8; ++i) {
          int jj = jt * 32 + quad * 8 + i;
          a[i] = (short)f2bf(sm.kxqx[jj][d] * sm.kxqx[jj][e]);  // chi (psi carries 0.5)
        }
        afr[mm] = a;
      }
#pragma unroll
      for (int nt = 0; nt < 5; ++nt) {
        int ncol = nt * 16 + n16;
        short8 b = zero8();
        if (ncol < NZ) b = *(const short8*)(&sm.vt[ncol][jt * 32 + quad * 8]);
        acc[0][nt] = __builtin_amdgcn_mfma_f32_16x16x32_bf16(afr[0], b, acc[0][nt], 0, 0, 0);
        acc[1][nt] = __builtin_amdgcn_mfma_f32_16x16x32_bf16(afr[1], b, acc[1][nt], 0, 0, 0);
      }
    }
    unsigned short* stc = st + (size_t)(bh * NC + c) * PER;
#pragma unroll
    for (int mm = 0; mm < 2; ++mm)
#pragma unroll
      for (int nt = 0; nt < 5; ++nt) {
        int col = nt * 16 + n16;
        if (col < NZ) {
          unsigned lo = f2bf(acc[mm][nt][0]) | (f2bf(acc[mm][nt][1]) << 16);
          unsigned hi = f2bf(acc[mm][nt][2]) | (f2bf(acc[mm][nt][3]) << 16);
          int feat0 = (w * 2 + mm) * 16 + quad * 4;
          *(uint2*)(stc + (size_t)col * NF + feat0) = make_uint2(lo, hi);
        }
      }
  }
  __syncthreads();   // kx fully consumed -> safe to overwrite with qx

  // qx load (pre-sync: hides global q latency under the grid barrier)
  {
    const float* qc = q + base * D;
    for (int i = t; i < CS * D; i += 512) {
      int row = i >> 4, dd = i & 15;
      sm.kxqx[row][dd] = qc[i] * 0.25f;      // d^-0.5; cols 16/17 still 1/0
    }
  }

  // ---------------- grid-wide barrier ----------------
  cooperative_groups::this_grid().sync();

  // ---------------- Phase B: latency-parallel prefix sum into LDS ----------------
  if (c > 0) {
    const unsigned short* stg = st + (size_t)bh * NC * PER;
    float s0[8], s1[8], s2[8];
#pragma unroll
    for (int e = 0; e < 8; ++e) { s0[e] = 0.f; s1[e] = 0.f; s2[e] = 0.f; }
    const int i0 = t * 8, i1 = i0 + 4096, i2 = i0 + 8192;
    const bool h2 = (i2 < PER);
    for (int cc = 0; cc < c; ++cc) {
      const unsigned short* pcc = stg + (size_t)cc * PER;
      short8 a0 = *(const short8*)(pcc + i0);
      short8 a1 = *(const short8*)(pcc + i1);
      short8 a2 = h2 ? *(const short8*)(pcc + i2) : zero8();
#pragma unroll
      for (int e = 0; e < 8; ++e) {
        s0[e] += bf2f((unsigned short)a0[e]);
        s1[e] += bf2f((unsigned short)a1[e]);
        s2[e] += bf2f((unsigned short)a2[e]);
      }
    }
    {
      int col = i0 / NF, ft = i0 - col * NF;
      short8 p;
#pragma unroll
      for (int e = 0; e < 8; ++e) p[e] = (short)f2bf(s0[e]);
      *(short8*)(&sm.b.stt[col][ft]) = p;
      col = i1 / NF; ft = i1 - col * NF;
#pragma unroll
      for (int e = 0; e < 8; ++e) p[e] = (short)f2bf(s1[e]);
      *(short8*)(&sm.b.stt[col][ft]) = p;
      if (h2) {
        col = i2 / NF; ft = i2 - col * NF;
#pragma unroll
        for (int e = 0; e < 8; ++e) p[e] = (short)f2bf(s2[e]);
        *(short8*)(&sm.b.stt[col][ft]) = p;
      }
    }
  }
  __syncthreads();

  // ---------------- Phase C ----------------
  f32x4 acc[2][5];
#pragma unroll
  for (int mm = 0; mm < 2; ++mm)
#pragma unroll
    for (int nt = 0; nt < 5; ++nt) acc[mm][nt] = (f32x4){0.f, 0.f, 0.f, 0.f};

  // inter: acc += psi(Q) · S_prefix   (skip chunk 0)
  if (c > 0) {
    for (int ks = 0; ks < KSTEPS; ++ks) {
      short8 afr[2];
#pragma unroll
      for (int mm = 0; mm < 2; ++mm) {
        const float* qrow = sm.kxqx[(w * 2 + mm) * 16 + n16];
        short8 a;
#pragma unroll
        for (int i = 0; i < 8; ++i) {
          int f = ks * 32 + quad * 8 + i;
          unsigned tv = sm.tbl[f];
          float val = qrow[tv & 255] * qrow[(tv >> 8) & 255];
          if (tv & 0x10000u) val *= 0.5f;
          a[i] = (short)f2bf(val);
        }
        afr[mm] = a;
      }
#pragma unroll
      for (int nt = 0; nt < 5; ++nt) {
        int ncol = nt * 16 + n16;
        short8 b = zero8();
        if (ncol < NZ) b = *(const short8*)(&sm.b.stt[ncol][ks * 32 + quad * 8]);
        acc[0][nt] = __builtin_amdgcn_mfma_f32_16x16x32_bf16(afr[0], b, acc[0][nt], 0, 0, 0);
        acc[1][nt] = __builtin_amdgcn_mfma_f32_16x16x32_bf16(afr[1], b, acc[1][nt], 0, 0, 0);
      }
    }
  }
  __syncthreads();   // stt fully consumed -> ptile may alias it

  // intra: causal phi attention, j-tiles of 32 keys, jt <= w
  short8 qfr[2];
#pragma unroll
  for (int mm = 0; mm < 2; ++mm) {
    int m = (w * 2 + mm) * 16 + n16;
    short8 a = zero8();
    if (quad < 2) {
#pragma unroll
      for (int i = 0; i < 8; ++i) a[i] = (short)f2bf(sm.kxqx[m][quad * 8 + i]);
    }
    qfr[mm] = a;
  }
  const unsigned short* kbc = (const unsigned short*)kbf_u32 + base * D;
  unsigned short* pw = &sm.b.u.ptile[w][0];
  short8 ones;
#pragma unroll
  for (int i = 0; i < 8; ++i) ones[i] = (short)0x3F80;

  for (int jt = 0; jt <= w; ++jt) {
    short8 kb[2];
#pragma unroll
    for (int ntk = 0; ntk < 2; ++ntk) {
      short8 b = zero8();
      if (quad < 2)
        b = *(const short8*)(kbc + (size_t)(jt * 32 + ntk * 16 + n16) * D + quad * 8);
      kb[ntk] = b;
    }
    f32x4 zf = (f32x4){0.f, 0.f, 0.f, 0.f};
    f32x4 s[2][2];
#pragma unroll
    for (int mm = 0; mm < 2; ++mm)
#pragma unroll
      for (int ntk = 0; ntk < 2; ++ntk)
        s[mm][ntk] = __builtin_amdgcn_mfma_f32_16x16x32_bf16(qfr[mm], kb[ntk], zf, 0, 0, 0);
    bool diag = (jt == w);
#pragma unroll
    for (int mm = 0; mm < 2; ++mm)
#pragma unroll
      for (int ntk = 0; ntk < 2; ++ntk)
#pragma unroll
        for (int r = 0; r < 4; ++r) {
          float sv = s[mm][ntk][r];
          float phi = fmaf(0.5f * sv, sv, sv) + 1.0f;
          if (diag) {
            int qrow = mm * 16 + quad * 4 + r;
            int kcol = ntk * 16 + n16;
            if (kcol > qrow) phi = 0.f;
          }
          pw[(mm * 16 + quad * 4 + r) * 40 + ntk * 16 + n16] = (unsigned short)f2bf(phi);
        }
    short8 pa[2];
#pragma unroll
    for (int mm = 0; mm < 2; ++mm)
      pa[mm] = *(const short8*)(pw + (mm * 16 + n16) * 40 + quad * 8);
#pragma unroll
    for (int nt = 0; nt < 5; ++nt) {
      int ncol = nt * 16 + n16;
      short8 b;
      if (ncol < 64)       b = *(const short8*)(&sm.vt[ncol][jt * 32 + quad * 8]);
      else if (ncol == 64) b = ones;
      else                 b = zero8();
      acc[0][nt] = __builtin_amdgcn_mfma_f32_16x16x32_bf16(pa[0], b, acc[0][nt], 0, 0, 0);
      acc[1][nt] = __builtin_amdgcn_mfma_f32_16x16x32_bf16(pa[1], b, acc[1][nt], 0, 0, 0);
    }
  }

  // epilogue: z broadcast via per-wave LDS rows, normalize, store
  if (n16 == 0) {
#pragma unroll
    for (int mm = 0; mm < 2; ++mm)
#pragma unroll
      for (int r = 0; r < 4; ++r)
        sm.b.u.zline[(w * 2 + mm) * 16 + quad * 4 + r] = acc[mm][4][r];
  }
  float* oc = out + base * DV;
#pragma unroll
  for (int mm = 0; mm < 2; ++mm)
#pragma unroll
    for (int r = 0; r < 4; ++r) {
      int qrow = (w * 2 + mm) * 16 + quad * 4 + r;
      float inv = 1.0f / (sm.b.u.zline[qrow] + 1e-6f);
#pragma unroll
      for (int nt = 0; nt < 4; ++nt)
        oc[(size_t)qrow * DV + nt * 16 + n16] = acc[mm][nt][r] * inv;
    }
}

// =================== FALLBACK: proven R5 3-kernel path ===================
__global__ __launch_bounds__(320) void pass_a(const float* __restrict__ k,
                                              const float* __restrict__ v,
                                              unsigned* __restrict__ kbf_u32,
                                              unsigned* __restrict__ vt_u32,
                                              unsigned short* __restrict__ st) {
  __shared__ float kx[CS][18];
  __shared__ __align__(16) unsigned short vt_lds[NZ][264];
  __shared__ unsigned tbl[NF];
  int blk = blockIdx.x, bh = blk >> 4, c = blk & 15;
  int t = threadIdx.x, w = t >> 6, lane = t & 63, quad = lane >> 4, n16 = lane & 15;
  {
    const float2* kc2 = (const float2*)(k + ((size_t)bh * LSEQ + c * CS) * D);
    unsigned* kbd = kbf_u32 + ((size_t)bh * LSEQ + c * CS) * D / 2;
    for (int i = t; i < 2048; i += 320) {
      float2 v2 = kc2[i];
      kbd[i] = f2bf(v2.x) | (f2bf(v2.y) << 16);
      int j = i >> 3, dd = (i & 7) * 2;
      kx[j][dd] = v2.x; kx[j][dd + 1] = v2.y;
    }
    for (int i = t; i < CS; i += 320) { kx[i][16] = 1.f; kx[i][17] = 0.f; }
  }
  {
    const float* vb = v + ((size_t)bh * LSEQ + c * CS) * DV;
    for (int i = t; i < CS * DV; i += 320) {
      int j = i >> 6, f = i & 63;
      vt_lds[f][j] = (unsigned short)f2bf(vb[i]);
    }
    for (int i = t; i < CS; i += 320) vt_lds[64][i] = (unsigned short)0x3F80;
  }
  if (t < NF) tbl[t] = feat_tbl(t);
  __syncthreads();
  {
    unsigned* vtg = vt_u32 + (size_t)bh * NZ * (LSEQ / 2) + c * (CS / 2);
    for (int i = t; i < NZ * (CS / 2); i += 320) {
      int f = i >> 7, jp = (i & 127) * 2;
      vtg[(size_t)f * (LSEQ / 2) + (i & 127)] =
          (unsigned)vt_lds[f][jp] | ((unsigned)vt_lds[f][jp + 1] << 16);
    }
  }
  f32x4 acc[2][5];
#pragma unroll
  for (int mm = 0; mm < 2; ++mm)
#pragma unroll
    for (int nt = 0; nt < 5; ++nt) acc[mm][nt] = (f32x4){0.f, 0.f, 0.f, 0.f};
  for (int jt = 0; jt < 8; ++jt) {
    short8 afr[2];
#pragma unroll
    for (int mm = 0; mm < 2; ++mm) {
      int feat = (w * 2 + mm) * 16 + n16;
      unsigned tv = tbl[feat];
      int d = tv & 255, e = (tv >> 8) & 255;
      short8 a;
#pragma unroll
      for (int i = 0; i < 8; ++i) {
        int jj = jt * 32 + quad * 8 + i;
        a[i] = (short)f2bf(kx[jj][d] * kx[jj][e]);
      }
      afr[mm] = a;
    }
#pragma unroll
    for (int nt = 0; nt < 5; ++nt) {
      int ncol = nt * 16 + n16;
      short8 b = zero8();
      if (ncol < NZ) b = *(const short8*)(&vt_lds[ncol][jt * 32 + quad * 8]);
      acc[0][nt] = __builtin_amdgcn_mfma_f32_16x16x32_bf16(afr[0], b, acc[0][nt], 0, 0, 0);
      acc[1][nt] = __builtin_amdgcn_mfma_f32_16x16x32_bf16(afr[1], b, acc[1][nt], 0, 0, 0);
    }
  }
  unsigned short* stc = st + (size_t)(bh * NC + c) * PER;
#pragma unroll
  for (int mm = 0; mm < 2; ++mm)
#pragma unroll
    for (int nt = 0; nt < 5; ++nt) {
      int col = nt * 16 + n16;
      if (col < NZ) {
        unsigned lo = f2bf(acc[mm][nt][0]) | (f2bf(acc[mm][nt][1]) << 16);
        unsigned hi = f2bf(acc[mm][nt][2]) | (f2bf(acc[mm][nt][3]) << 16);
        int feat0 = (w * 2 + mm) * 16 + quad * 4;
        *(uint2*)(stc + (size_t)col * NF + feat0) = make_uint2(lo, hi);
      }
    }
}

__global__ __launch_bounds__(256) void pass_b(unsigned short* __restrict__ st) {
  const int TOT = BH * PER;
  int idx = blockIdx.x * 256 + threadIdx.x;
  if (idx >= TOT) return;
  int bh = idx / PER, r = idx - bh * PER;
  unsigned short* p = st + (size_t)bh * NC * PER + r;
  float run = 0.f;
#pragma unroll
  for (int c = 0; c < NC; ++c) {
    unsigned short uv = p[(size_t)c * PER];
    float val = bf2f(uv);
    p[(size_t)c * PER] = (unsigned short)f2bf(run);
    run += val;
  }
}

__global__ __launch_bounds__(512) void pass_c(const float* __restrict__ q,
                                              const unsigned short* __restrict__ kbf,
                                              const unsigned short* __restrict__ vt,
                                              const unsigned short* __restrict__ st,
                                              float* __restrict__ out) {
  __shared__ float qx[CS][18];
  __shared__ unsigned tbl[NF];
  __shared__ __align__(16) unsigned short ptile[8][32 * 40];
  __shared__ float zline[CS];
  int blk = blockIdx.x, bh = blk >> 4, c = blk & 15;
  const size_t base = (size_t)bh * LSEQ + (size_t)c * CS;
  const float* qc = q + base * D;
  int t = threadIdx.x, w = t >> 6, lane = t & 63, quad = lane >> 4, n16 = lane & 15;
  for (int i = t; i < CS * D; i += 512) {
    int row = i >> 4, dd = i & 15;
    qx[row][dd] = qc[i] * 0.25f;
  }
  for (int i = t; i < CS; i += 512) { qx[i][16] = 1.f; qx[i][17] = 0.f; }
  if (t < NF) tbl[t] = feat_tbl(t);
  __syncthreads();
  f32x4 acc[2][5];
#pragma unroll
  for (int mm = 0; mm < 2; ++mm)
#pragma unroll
    for (int nt = 0; nt < 5; ++nt) acc[mm][nt] = (f32x4){0.f, 0.f, 0.f, 0.f};
  if (c > 0) {
    const unsigned short* stc = st + (size_t)(bh * NC + c) * PER;
    for (int ks = 0; ks < KSTEPS; ++ks) {
      short8 afr[2];
#pragma unroll
      for (int mm = 0; mm < 2; ++mm) {
        const float* qrow = qx[(w * 2 + mm) * 16 + n16];
        short8 a;
#pragma unroll
        for (int i = 0; i < 8; ++i) {
          int f = ks * 32 + quad * 8 + i;
          unsigned tv = tbl[f];
          float val = qrow[tv & 255] * qrow[(tv >> 8) & 255];
          if (tv & 0x10000u) val *= 0.5f;
          a[i] = (short)f2bf(val);
        }
        afr[mm] = a;
      }
#pragma unroll
      for (int nt = 0; nt < 5; ++nt) {
        int ncol = nt * 16 + n16;
        short8 b = zero8();
        if (ncol < NZ) b = *(const short8*)(stc + (size_t)ncol * NF + ks * 32 + quad * 8);
        acc[0][nt] = __builtin_amdgcn_mfma_f32_16x16x32_bf16(afr[0], b, acc[0][nt], 0, 0, 0);
        acc[1][nt] = __builtin_amdgcn_mfma_f32_16x16x32_bf16(afr[1], b, acc[1][nt], 0, 0, 0);
      }
    }
  }
  short8 qfr[2];
#pragma unroll
  for (int mm = 0; mm < 2; ++mm) {
    int m = (w * 2 + mm) * 16 + n16;
    short8 a = zero8();
    if (quad < 2) {
#pragma unroll
      for (int i = 0; i < 8; ++i) a[i] = (short)f2bf(qx[m][quad * 8 + i]);
    }
    qfr[mm] = a;
  }
  const unsigned short* kbc = kbf + base * D;
  const unsigned short* vtb = vt + (size_t)bh * NZ * LSEQ + (size_t)c * CS;
  unsigned short* pw = &ptile[w][0];
  short8 ones;
#pragma unroll
  for (int i = 0; i < 8; ++i) ones[i] = (short)0x3F80;
  for (int jt = 0; jt <= w; ++jt) {
    short8 kb[2];
#pragma unroll
    for (int ntk = 0; ntk < 2; ++ntk) {
      short8 b = zero8();
      if (quad < 2)
        b = *(const short8*)(kbc + (size_t)(jt * 32 + ntk * 16 + n16) * D + quad * 8);
      kb[ntk] = b;
    }
    f32x4 zf = (f32x4){0.f, 0.f, 0.f, 0.f};
    f32x4 s[2][2];
#pragma unroll
    for (int mm = 0; mm < 2; ++mm)
#pragma unroll
      for (int ntk = 0; ntk < 2; ++ntk)
        s[mm][ntk] = __builtin_amdgcn_mfma_f32_16x16x32_bf16(qfr[mm], kb[ntk], zf, 0, 0, 0);
    bool diag = (jt == w);
#pragma unroll
    for (int mm = 0; mm < 2; ++mm)
#pragma unroll
      for (int ntk = 0; ntk < 2; ++ntk)
#pragma unroll
        for (int r = 0; r < 4; ++r) {
          float sv = s[mm][ntk][r];
          float phi = fmaf(0.5f * sv, sv, sv) + 1.0f;
          if (diag) {
            int qrow = mm * 16 + quad * 4 + r;
            int kcol = ntk * 16 + n16;
            if (kcol > qrow) phi = 0.f;
          }
          pw[(mm * 16 + quad * 4 + r) * 40 + ntk * 16 + n16] = (unsigned short)f2bf(phi);
        }
    short8 pa[2];
#pragma unroll
    for (int mm = 0; mm < 2; ++mm)
      pa[mm] = *(const short8*)(pw + (mm * 16 + n16) * 40 + quad * 8);
#pragma unroll
    for (int nt = 0; nt < 5; ++nt) {
      int ncol = nt * 16 + n16;
      short8 b;
      if (ncol < 64)       b = *(const short8*)(vtb + (size_t)ncol * LSEQ + jt * 32 + quad * 8);
      else if (ncol == 64) b = ones;
      else                 b = zero8();
      acc[0][nt] = __builtin_amdgcn_mfma_f32_16x16x32_bf16(pa[0], b, acc[0][nt], 0, 0, 0);
      acc[1][nt] = __builtin_amdgcn_mfma_f32_16x16x32_bf16(pa[1], b, acc[1][nt], 0, 0, 0);
    }
  }
  if (n16 == 0) {
#pragma unroll
    for (int mm = 0; mm < 2; ++mm)
#pragma unroll
      for (int r = 0; r < 4; ++r)
        zline[(w * 2 + mm) * 16 + quad * 4 + r] = acc[mm][4][r];
  }
  float* oc = out + base * DV;
#pragma unroll
  for (int mm = 0; mm < 2; ++mm)
#pragma unroll
    for (int r = 0; r < 4; ++r) {
      int qrow = (w * 2 + mm) * 16 + quad * 4 + r;
      float inv = 1.0f / (zline[qrow] + 1e-6f);
#pragma unroll
      for (int nt = 0; nt < 4; ++nt)
        oc[(size_t)qrow * DV + nt * 16 + n16] = acc[mm][nt][r] * inv;
    }
}

extern "C" void kernel_launch(void* const* d_in, const int* in_sizes, int n_in,
                              void* d_out, int out_size, void* d_ws, size_t ws_size,
                              hipStream_t stream) {
  (void)in_sizes; (void)n_in; (void)out_size; (void)ws_size;
  const float* q = (const float*)d_in[0];
  const float* k = (const float*)d_in[1];
  const float* v = (const float*)d_in[2];
  float* out = (float*)d_out;
  char* wsb = (char*)d_ws;
  unsigned*       kbf32 = (unsigned*)(wsb + OFF_KBF);
  unsigned short* kbf   = (unsigned short*)(wsb + OFF_KBF);
  unsigned*       vt32  = (unsigned*)(wsb + OFF_VT);
  unsigned short* vtp   = (unsigned short*)(wsb + OFF_VT);
  unsigned short* stp   = (unsigned short*)(wsb + OFF_ST);

  // deterministic per-call path choice (same result every call -> capture-safe)
  int nb = 0;
  hipError_t oe = hipOccupancyMaxActiveBlocksPerMultiprocessor(
      &nb, reinterpret_cast<const void*>(unified), 512, 0);
  if (oe == hipSuccess && nb >= 2) {
    void* args[] = {(void*)&q, (void*)&k, (void*)&v,
                    (void*)&kbf32, (void*)&stp, (void*)&out};
    hipLaunchCooperativeKernel(reinterpret_cast<const void*>(unified),
                               dim3(BH * NC), dim3(512), args, 0, stream);
  } else {
    pass_a<<<BH * NC, 320, 0, stream>>>(k, v, kbf32, vt32, stp);
    pass_b<<<1300, 256, 0, stream>>>(stp);
    pass_c<<<BH * NC, 512, 0, stream>>>(q, kbf, vtp, stp, out);
  }
}